// Round 5
// baseline (369.543 us; speedup 1.0000x reference)
//
#include <hip/hip_runtime.h>
#include <hip/hip_bf16.h>
#include <stdint.h>

#define DIM 1024
#define NH 16
#define NKV 4
#define HD 64
#define SEQ 2048
#define BATCH 2
#define RANK 4
#define NSTEPS 2
#define MASKF (-3.0e38f)

// bf16 conversion-region element offsets (compile-time)
#define XN      4194304            // x: 4096*1024
#define WQ_END  5242880            // + 1024*1024
#define WK_END  5505024            // + 256*1024
#define WV_END  5767168            // + 256*1024
#define CVT_BLOCKS 6656            // CVT_TOT/1024
#define LORA_BLOCKS 1024

typedef unsigned short u16;
typedef unsigned int u32;
typedef __attribute__((ext_vector_type(8))) __bf16 bf16x8;
typedef __attribute__((ext_vector_type(4))) float f32x4;

__device__ __forceinline__ float bf2f(u16 v) {
    u32 u = ((u32)v) << 16;
    return __builtin_bit_cast(float, u);
}
__device__ __forceinline__ u16 f2bf(float f) {
    u32 u = __builtin_bit_cast(u32, f);
    u32 r = (u + 0x7fffu + ((u >> 16) & 1u)) >> 16;
    return (u16)r;
}
__device__ __forceinline__ u32 pk2(float a, float b) {
    return (u32)f2bf(a) | ((u32)f2bf(b) << 16);
}

// ---------------- K_PREP: fused [fp32->bf16 convert | LoRA t = x@A^T] -------
__global__ __launch_bounds__(256) void k_prep(
    const float* __restrict__ x, const float* __restrict__ Wq,
    const float* __restrict__ Wk, const float* __restrict__ Wv,
    const float* __restrict__ Wp, u16* __restrict__ dst,
    const float* __restrict__ Aq, const float* __restrict__ Av,
    const int* __restrict__ step_p, float* __restrict__ tq, float* __restrict__ tv)
{
    int bx = blockIdx.x;
    if (bx < CVT_BLOCKS) {
        int e = (bx * 256 + threadIdx.x) * 4;
        const float* src;
        if (e < XN)          src = x  + e;
        else if (e < WQ_END) src = Wq + (e - XN);
        else if (e < WK_END) src = Wk + (e - WQ_END);
        else if (e < WV_END) src = Wv + (e - WK_END);
        else                 src = Wp + (e - WV_END);
        float4 v = *(const float4*)src;
        *(uint2*)(dst + e) = make_uint2(pk2(v.x, v.y), pk2(v.z, v.w));
        return;
    }
    // ---- LoRA path ----
    int wave = ((bx - CVT_BLOCKS) * 256 + threadIdx.x) >> 6;   // row 0..4095
    int lane = threadIdx.x & 63;
    int step = step_p[0];
    int valid = (step >= 0 && step < NSTEPS);
    int sc = valid ? step : 0;
    const float* xr = x + wave * DIM + lane * 16;
    float xf[16];
#pragma unroll
    for (int q = 0; q < 4; q++) {
        float4 v4 = *(const float4*)(xr + q * 4);
        xf[q * 4 + 0] = v4.x; xf[q * 4 + 1] = v4.y;
        xf[q * 4 + 2] = v4.z; xf[q * 4 + 3] = v4.w;
    }
    float sums[8];
#pragma unroll
    for (int j = 0; j < 8; j++) {
        const float* ar = (j < 4 ? Aq + sc * RANK * DIM + j * DIM
                                 : Av + sc * RANK * DIM + (j - 4) * DIM) + lane * 16;
        float s = 0.f;
#pragma unroll
        for (int q = 0; q < 4; q++) {
            float4 a4 = *(const float4*)(ar + q * 4);
            s += xf[q * 4 + 0] * a4.x + xf[q * 4 + 1] * a4.y
               + xf[q * 4 + 2] * a4.z + xf[q * 4 + 3] * a4.w;
        }
#pragma unroll
        for (int o = 32; o > 0; o >>= 1) s += __shfl_xor(s, o, 64);
        sums[j] = s;
    }
    if (!valid) {
#pragma unroll
        for (int j = 0; j < 8; j++) sums[j] = 0.f;
    }
    if (lane == 0) {
        tq[wave * 4 + 0] = sums[0]; tq[wave * 4 + 1] = sums[1];
        tq[wave * 4 + 2] = sums[2]; tq[wave * 4 + 3] = sums[3];
        tv[wave * 4 + 0] = sums[4]; tv[wave * 4 + 1] = sums[5];
        tv[wave * 4 + 2] = sums[6]; tv[wave * 4 + 3] = sums[7];
    }
}

// ---------------- GEMM: C[M][N] = A[M][1024] * B[N][1024]^T, bf16 in, fp32 acc
// 128x128 tile, BK=64, double-buffered LDS, ONE barrier per K-step.
template<bool CF32>
__global__ __launch_bounds__(256) void k_gemm(
    const u16* __restrict__ A, const u16* __restrict__ B,
    void* __restrict__ Cptr, int Ntiles, int N)
{
    __shared__ __align__(16) u16 As[2][8192];
    __shared__ __align__(16) u16 Bs[2][8192];
    int bx = blockIdx.x;
    int bn = bx % Ntiles, bm = bx / Ntiles;
    int t = threadIdx.x, lane = t & 63, w = t >> 6;
    int wy = w >> 1, wx = w & 1;
    f32x4 acc[4][4];
#pragma unroll
    for (int i = 0; i < 4; i++)
#pragma unroll
        for (int j = 0; j < 4; j++) acc[i][j] = (f32x4){0.f, 0.f, 0.f, 0.f};

    uint4 ra[4], rb[4];
    auto gload = [&](int kb) {
#pragma unroll
        for (int u = 0; u < 4; u++) {
            int idx = u * 256 + t;
            int grp = idx >> 6;
            int mt = grp >> 1, c = grp & 1;
            int quad = (idx >> 4) & 3, m = idx & 15;
            int row = mt * 16 + m;
            int k0 = kb * 64 + c * 32 + quad * 8;
            ra[u] = *(const uint4*)(A + (bm * 128 + row) * DIM + k0);
            rb[u] = *(const uint4*)(B + (bn * 128 + row) * DIM + k0);
        }
    };
    gload(0);
#pragma unroll 1
    for (int kb = 0; kb < 16; kb++) {
        int cb = kb & 1;
#pragma unroll
        for (int u = 0; u < 4; u++) {
            int idx = u * 256 + t;
            *(uint4*)(As[cb] + idx * 8) = ra[u];
            *(uint4*)(Bs[cb] + idx * 8) = rb[u];
        }
        __syncthreads();
        if (kb < 15) gload(kb + 1);   // async; consumed by next iter's ds_write
#pragma unroll
        for (int c = 0; c < 2; c++) {
            bf16x8 af[4], bfr[4];
#pragma unroll
            for (int i = 0; i < 4; i++) {
                int mt = wy * 4 + i;
                af[i] = *(bf16x8*)(As[cb] + ((mt * 2 + c) * 64 + lane) * 8);
                int nt = wx * 4 + i;
                bfr[i] = *(bf16x8*)(Bs[cb] + ((nt * 2 + c) * 64 + lane) * 8);
            }
#pragma unroll
            for (int i = 0; i < 4; i++)
#pragma unroll
                for (int j = 0; j < 4; j++)
                    acc[i][j] = __builtin_amdgcn_mfma_f32_16x16x32_bf16(af[i], bfr[j], acc[i][j], 0, 0, 0);
        }
    }
    int quad = lane >> 4, n16 = lane & 15;
#pragma unroll
    for (int i = 0; i < 4; i++) {
#pragma unroll
        for (int j = 0; j < 4; j++) {
            int col = bn * 128 + wx * 64 + j * 16 + n16;
#pragma unroll
            for (int r = 0; r < 4; r++) {
                int rowm = bm * 128 + wy * 64 + i * 16 + quad * 4 + r;
                if (CF32) ((float*)Cptr)[rowm * N + col] = acc[i][j][r];
                else      ((u16*)Cptr)[rowm * N + col] = f2bf(acc[i][j][r]);
            }
        }
    }
}

// ---------------- K_POST: fused [RMSNorm+RoPE in-place | v-LoRA+transpose] ---
#define NR_BLOCKS 20480
__global__ __launch_bounds__(256) void k_post(
    u16* __restrict__ qkv,
    const float* __restrict__ tq, const float* __restrict__ Bq,
    const float* __restrict__ gain,
    const float* __restrict__ tv, const float* __restrict__ Bv,
    const int* __restrict__ step_p, u16* __restrict__ vt)
{
    __shared__ __align__(16) u16 tile[64 * 64];
    int bx = blockIdx.x;
    int step = step_p[0];
    int valid = (step >= 0 && step < NSTEPS);
    int sc = valid ? step : 0;
    if (bx < NR_BLOCKS) {
        int wid = (bx * 256 + threadIdx.x) >> 6;
        int lane = threadIdx.x & 63;
        float val, postmul;
        u16* ptr;
        int s;
        if (wid < BATCH * NH * SEQ) {
            int b = wid >> 15;
            int h = (wid >> 11) & 15;
            s = wid & 2047;
            int row = b * SEQ + s;
            ptr = qkv + row * 1536 + h * HD + lane;
            val = bf2f(*ptr);
            const float* tr = tq + row * 4;
            float4 br = *(const float4*)(Bq + sc * DIM * RANK + (h * HD + lane) * RANK);
            val += tr[0] * br.x + tr[1] * br.y + tr[2] * br.z + tr[3] * br.w;
            postmul = gain[h] * 0.125f * 1.4426950408889634f;   // gain/sqrt(64)*log2e
        } else {
            int wk = wid - BATCH * NH * SEQ;
            int b = wk >> 13;
            int h = (wk >> 11) & 3;
            s = wk & 2047;
            int row = b * SEQ + s;
            ptr = qkv + row * 1536 + 1024 + h * HD + lane;
            val = bf2f(*ptr);
            postmul = 1.f;
        }
        float ss = val * val;
#pragma unroll
        for (int o = 32; o > 0; o >>= 1) ss += __shfl_xor(ss, o, 64);
        float rr = rsqrtf(ss * (1.f / 64.f) + 1.1920928955078125e-7f);
        float vn = val * rr;
        float partner = __shfl_xor(vn, 16, 64);
        float res;
        if (lane < 32) {
            int i = lane & 15;
            float invf = exp2f(-(float)i * 0.8304820237218405f);  // log2(10000)/16
            float ang = (float)s * invf;
            float cs = cosf(ang), sn = sinf(ang);
            res = (lane < 16) ? (vn * cs + partner * sn) : (-partner * sn + vn * cs);
        } else {
            res = vn;
        }
        *ptr = f2bf(res * postmul);
        return;
    }
    // ---- v transpose path ----
    int vb = bx - NR_BLOCKS;
    int st = vb & 31, g = (vb >> 5) & 3, b = vb >> 7;
    int t = threadIdx.x;
    int s_l = t & 63, dq = t >> 6;
    int row = b * SEQ + st * 64 + s_l;
    const float* tr = tv + row * 4;
    float t0 = tr[0], t1 = tr[1], t2 = tr[2], t3 = tr[3];
    const u16* src = qkv + row * 1536 + 1280 + g * HD + dq * 16;
#pragma unroll
    for (int e = 0; e < 16; e++) {
        int d = dq * 16 + e;
        float4 br = *(const float4*)(Bv + sc * (NKV * HD) * RANK + (g * HD + d) * RANK);
        float v = bf2f(src[e]) + t0 * br.x + t1 * br.y + t2 * br.z + t3 * br.w;
        tile[d * 64 + s_l] = f2bf(v);
    }
    __syncthreads();
#pragma unroll
    for (int u = 0; u < 2; u++) {
        int chunk = u * 256 + t;
        int d = chunk >> 3, scn = chunk & 7;
        *(uint4*)(vt + ((b * NKV + g) * HD + d) * SEQ + st * 64 + scn * 8) =
            *(uint4*)(tile + d * 64 + scn * 8);
    }
}

// ---------------- ATT helpers ----------------------------------------------
__device__ __forceinline__ void softmax_step(
    f32x4* st, float& m_run, float& l_run, f32x4* yacc, u16* pw, int quad, int n16)
{
    float tm = st[0][0];
#pragma unroll
    for (int nt = 0; nt < 4; nt++)
#pragma unroll
        for (int r = 0; r < 4; r++) tm = fmaxf(tm, st[nt][r]);
    tm = fmaxf(tm, __shfl_xor(tm, 16, 64));
    tm = fmaxf(tm, __shfl_xor(tm, 32, 64));
    float m_new = fmaxf(m_run, tm);
    float alpha = exp2f(m_run - m_new);
    m_run = m_new;
    float tsum = 0.f;
    float p[4][4];
#pragma unroll
    for (int nt = 0; nt < 4; nt++)
#pragma unroll
        for (int r = 0; r < 4; r++) {
            float e = exp2f(st[nt][r] - m_new);
            p[nt][r] = e;
            tsum += e;
        }
    tsum += __shfl_xor(tsum, 16, 64);
    tsum += __shfl_xor(tsum, 32, 64);
    l_run = l_run * alpha + tsum;
#pragma unroll
    for (int i = 0; i < 4; i++) {
        yacc[i][0] *= alpha; yacc[i][1] *= alpha;
        yacc[i][2] *= alpha; yacc[i][3] *= alpha;
    }
#pragma unroll
    for (int nt = 0; nt < 4; nt++) {
        u32 lo = pk2(p[nt][0], p[nt][1]);
        u32 hi = pk2(p[nt][2], p[nt][3]);
        int ck = nt >> 1;
        int qbk = (nt & 1) * 2 + (quad >> 1);
        int byteoff = (ck * 64 + qbk * 16 + n16) * 16 + (quad & 1) * 8;
        *(uint2*)((char*)pw + byteoff) = make_uint2(lo, hi);
    }
}

// ---------------- ATT: wave-per-block, dual-strip fused flash attention -----
// Block = 1 wave. 2048 blocks: (b,h,pr). Strips s0=pr (short) and s1=127-pr
// (long) share the kt loop; s0's tile range is a subset of s1's, so each K/V
// tile load serves BOTH strips (2x ILP, 2x fewer loads). K prefetched after
// S-MFMAs, V reloaded after PV (latency hidden behind softmax/MFMA).
__global__ __launch_bounds__(64) void k_attn(
    const u16* __restrict__ qkv, const u16* __restrict__ vt,
    u16* __restrict__ y)
{
    __shared__ __align__(16) u16 pb[2][1024];    // P^T per strip, B-frag linear
    int lane = threadIdx.x;
    int blk = blockIdx.x;
    int b = blk >> 10, h = (blk >> 6) & 15, pr = blk & 63;
    int g = h >> 2;
    int quad = lane >> 4, n16 = lane & 15;
    int s0 = pr, s1 = 127 - pr;
    int qrow0 = s0 * 16 + n16, qrow1 = s1 * 16 + n16;
    int niter0 = (s0 >> 2) + 1, niter1 = (s1 >> 2) + 1;
    const u16* kbase = qkv + b * SEQ * 1536 + 1024 + g * HD;   // K rows, stride 1536
    const u16* vbase = vt + (b * NKV + g) * HD * SEQ;          // V^T rows, stride 2048

    const u16* qp0 = qkv + (b * SEQ + qrow0) * 1536 + h * HD + quad * 8;
    const u16* qp1 = qkv + (b * SEQ + qrow1) * 1536 + h * HD + quad * 8;
    bf16x8 q0lo = *(const bf16x8*)qp0, q0hi = *(const bf16x8*)(qp0 + 32);
    bf16x8 q1lo = *(const bf16x8*)qp1, q1hi = *(const bf16x8*)(qp1 + 32);

    f32x4 acc0[4], acc1[4];
#pragma unroll
    for (int i = 0; i < 4; i++) {
        acc0[i] = (f32x4){0.f, 0.f, 0.f, 0.f};
        acc1[i] = (f32x4){0.f, 0.f, 0.f, 0.f};
    }
    float m0 = MASKF, l0 = 0.f, m1 = MASKF, l1 = 0.f;

    bf16x8 kfr[8], vfr[8];
    // preload tile 0
#pragma unroll
    for (int g16 = 0; g16 < 4; g16++)
#pragma unroll
        for (int c = 0; c < 2; c++)
            kfr[g16 * 2 + c] = *(const bf16x8*)(kbase + (g16 * 16 + n16) * 1536 + c * 32 + quad * 8);
#pragma unroll
    for (int dt = 0; dt < 4; dt++)
#pragma unroll
        for (int c = 0; c < 2; c++)
            vfr[dt * 2 + c] = *(const bf16x8*)(vbase + (dt * 16 + n16) * SEQ + c * 32 + quad * 8);

#pragma unroll 1
    for (int kt = 0; kt < niter1; kt++) {
        int k0 = kt * 64;
        bool a0 = (kt < niter0);
        int kn = (kt + 1 < niter1) ? (kt + 1) * 64 : kt * 64;   // clamped prefetch tile
        // S^T for both strips (st1 always, st0 while active)
        f32x4 st1[4], st0[4];
#pragma unroll
        for (int nt = 0; nt < 4; nt++) {
            f32x4 sa = (f32x4){0.f, 0.f, 0.f, 0.f};
            sa = __builtin_amdgcn_mfma_f32_16x16x32_bf16(kfr[nt * 2 + 0], q1lo, sa, 0, 0, 0);
            sa = __builtin_amdgcn_mfma_f32_16x16x32_bf16(kfr[nt * 2 + 1], q1hi, sa, 0, 0, 0);
            st1[nt] = sa;
        }
        if (a0) {
#pragma unroll
            for (int nt = 0; nt < 4; nt++) {
                f32x4 sa = (f32x4){0.f, 0.f, 0.f, 0.f};
                sa = __builtin_amdgcn_mfma_f32_16x16x32_bf16(kfr[nt * 2 + 0], q0lo, sa, 0, 0, 0);
                sa = __builtin_amdgcn_mfma_f32_16x16x32_bf16(kfr[nt * 2 + 1], q0hi, sa, 0, 0, 0);
                st0[nt] = sa;
            }
        }
        // prefetch next K tile (kfr free after S-MFMAs issued)
#pragma unroll
        for (int g16 = 0; g16 < 4; g16++)
#pragma unroll
            for (int c = 0; c < 2; c++)
                kfr[g16 * 2 + c] = *(const bf16x8*)(kbase + (kn + g16 * 16 + n16) * 1536 + c * 32 + quad * 8);
        // causal masks on diagonal tiles
        if (kt == niter1 - 1) {
#pragma unroll
            for (int nt = 0; nt < 4; nt++)
#pragma unroll
                for (int r = 0; r < 4; r++) {
                    int key = k0 + nt * 16 + quad * 4 + r;
                    st1[nt][r] = (key > qrow1) ? MASKF : st1[nt][r];
                }
        }
        if (a0 && kt == niter0 - 1) {
#pragma unroll
            for (int nt = 0; nt < 4; nt++)
#pragma unroll
                for (int r = 0; r < 4; r++) {
                    int key = k0 + nt * 16 + quad * 4 + r;
                    st0[nt][r] = (key > qrow0) ? MASKF : st0[nt][r];
                }
        }
        // two independent online-softmax chains (compiler interleaves)
        softmax_step(st1, m1, l1, acc1, pb[1], quad, n16);
        if (a0) softmax_step(st0, m0, l0, acc0, pb[0], quad, n16);
        asm volatile("s_waitcnt lgkmcnt(0)" ::: "memory");
        // PV for both strips (shared vfr)
#pragma unroll
        for (int ck = 0; ck < 2; ck++) {
            bf16x8 p1 = *(bf16x8*)(pb[1] + (ck * 64 + lane) * 8);
#pragma unroll
            for (int dt = 0; dt < 4; dt++)
                acc1[dt] = __builtin_amdgcn_mfma_f32_16x16x32_bf16(vfr[dt * 2 + ck], p1, acc1[dt], 0, 0, 0);
        }
        if (a0) {
#pragma unroll
            for (int ck = 0; ck < 2; ck++) {
                bf16x8 p0 = *(bf16x8*)(pb[0] + (ck * 64 + lane) * 8);
#pragma unroll
                for (int dt = 0; dt < 4; dt++)
                    acc0[dt] = __builtin_amdgcn_mfma_f32_16x16x32_bf16(vfr[dt * 2 + ck], p0, acc0[dt], 0, 0, 0);
            }
        }
        asm volatile("" ::: "memory");
        // prefetch next V tile (vfr free after PV issued)
#pragma unroll
        for (int dt = 0; dt < 4; dt++)
#pragma unroll
            for (int c = 0; c < 2; c++)
                vfr[dt * 2 + c] = *(const bf16x8*)(vbase + (dt * 16 + n16) * SEQ + kn + c * 32 + quad * 8);
    }
    float li1 = 1.f / l1, li0 = 1.f / l0;
#pragma unroll
    for (int dt = 0; dt < 4; dt++) {
        int d = dt * 16 + quad * 4;
        uint2 o1 = make_uint2(pk2(acc1[dt][0] * li1, acc1[dt][1] * li1),
                              pk2(acc1[dt][2] * li1, acc1[dt][3] * li1));
        *(uint2*)(y + (b * SEQ + qrow1) * DIM + h * HD + d) = o1;
        uint2 o0 = make_uint2(pk2(acc0[dt][0] * li0, acc0[dt][1] * li0),
                              pk2(acc0[dt][2] * li0, acc0[dt][3] * li0));
        *(uint2*)(y + (b * SEQ + qrow0) * DIM + h * HD + d) = o0;
    }
}

// ---------------------------------------------------------------------------
extern "C" void kernel_launch(void* const* d_in, const int* in_sizes, int n_in,
                              void* d_out, int out_size, void* d_ws, size_t ws_size,
                              hipStream_t stream)
{
    (void)in_sizes; (void)n_in; (void)out_size; (void)ws_size;
    const float* x     = (const float*)d_in[0];
    const float* Wq    = (const float*)d_in[1];
    const float* Wk    = (const float*)d_in[2];
    const float* Wv    = (const float*)d_in[3];
    const float* Wproj = (const float*)d_in[4];
    const float* qgain = (const float*)d_in[5];
    const float* Aq    = (const float*)d_in[6];
    const float* Bq    = (const float*)d_in[7];
    const float* Av    = (const float*)d_in[8];
    const float* Bv    = (const float*)d_in[9];
    const int*   step  = (const int*)d_in[10];

    // ws layout (25.1 MB):
    //  [0, 13631488)          bf16 cvt region: [xb 8MB | Wqkv 3MB | Wproj 2MB]
    //  [13631488, 26214400)   qkv bf16 [4096][1536] (12 MB)
    //  [26214400, 26345472)   tq, tv fp32 (64 KB each)
    //  reuse: y (8MB) overlays xb (dead after qkv GEMM);
    //         vt (2MB) overlays Wqkv (dead after qkv GEMM).
    char* ws = (char*)d_ws;
    u16* wsbf = (u16*)ws;
    u16* xb   = wsbf;                  // 4194304 elems
    u16* wf   = wsbf + XN;             // fused [Wq|Wk|Wv] 1536x1024
    u16* wp   = wsbf + WV_END;         // Wproj 1024x1024
    u16* qkv  = (u16*)(ws + 13631488); // [4096][1536]
    float* tq = (float*)(ws + 26214400);
    float* tv = tq + 16384;
    u16* y    = xb;                    // reuse
    u16* vt   = wf;                    // reuse: [2][4][64][2048]

    k_prep<<<CVT_BLOCKS + LORA_BLOCKS, 256, 0, stream>>>(x, Wq, Wk, Wv, Wproj, wsbf,
                                                         Aq, Av, step, tq, tv);
    k_gemm<false><<<384, 256, 0, stream>>>(xb, wf, qkv, 12, 1536);      // fused qkv
    k_post<<<NR_BLOCKS + 256, 256, 0, stream>>>(qkv, tq, Bq, qgain, tv, Bv, step, vt);
    k_attn<<<2048, 64, 0, stream>>>(qkv, vt, y);
    k_gemm<true><<<256, 256, 0, stream>>>(y, wp, d_out, 8, DIM);        // out proj
}

// Round 6
// 252.706 us; speedup vs baseline: 1.4623x; 1.4623x over previous
//
#include <hip/hip_runtime.h>
#include <hip/hip_bf16.h>
#include <stdint.h>

#define DIM 1024
#define NH 16
#define NKV 4
#define HD 64
#define SEQ 2048
#define BATCH 2
#define RANK 4
#define NSTEPS 2
#define MASKF (-3.0e38f)

// bf16 conversion-region element offsets (compile-time)
#define XN      4194304            // x: 4096*1024
#define WQ_END  5242880            // + 1024*1024
#define WK_END  5505024            // + 256*1024
#define WV_END  5767168            // + 256*1024
#define CVT_BLOCKS 6656
#define LORA_BLOCKS 1024

typedef unsigned short u16;
typedef unsigned int u32;
typedef __attribute__((ext_vector_type(8))) __bf16 bf16x8;
typedef __attribute__((ext_vector_type(4))) float f32x4;

__device__ __forceinline__ float bf2f(u16 v) {
    u32 u = ((u32)v) << 16;
    return __builtin_bit_cast(float, u);
}
__device__ __forceinline__ u16 f2bf(float f) {
    u32 u = __builtin_bit_cast(u32, f);
    u32 r = (u + 0x7fffu + ((u >> 16) & 1u)) >> 16;
    return (u16)r;
}
__device__ __forceinline__ u32 pk2(float a, float b) {
    return (u32)f2bf(a) | ((u32)f2bf(b) << 16);
}
// async global->LDS, 16 B per lane; lptr MUST be wave-uniform (HW adds lane*16)
__device__ __forceinline__ void glds16(const u16* g, u16* l) {
    __builtin_amdgcn_global_load_lds(
        (const __attribute__((address_space(1))) u32*)g,
        (__attribute__((address_space(3))) u32*)l, 16, 0, 0);
}

// ---------------- K_PREP: fused [fp32->bf16 convert | LoRA t = x@A^T] -------
__global__ __launch_bounds__(256) void k_prep(
    const float* __restrict__ x, const float* __restrict__ Wq,
    const float* __restrict__ Wk, const float* __restrict__ Wv,
    const float* __restrict__ Wp, u16* __restrict__ dst,
    const float* __restrict__ Aq, const float* __restrict__ Av,
    const int* __restrict__ step_p, float* __restrict__ tq, float* __restrict__ tv)
{
    int bx = blockIdx.x;
    if (bx < CVT_BLOCKS) {
        int e = (bx * 256 + threadIdx.x) * 4;
        const float* src;
        if (e < XN)          src = x  + e;
        else if (e < WQ_END) src = Wq + (e - XN);
        else if (e < WK_END) src = Wk + (e - WQ_END);
        else if (e < WV_END) src = Wv + (e - WK_END);
        else                 src = Wp + (e - WV_END);
        float4 v = *(const float4*)src;
        *(uint2*)(dst + e) = make_uint2(pk2(v.x, v.y), pk2(v.z, v.w));
        return;
    }
    int wave = ((bx - CVT_BLOCKS) * 256 + threadIdx.x) >> 6;
    int lane = threadIdx.x & 63;
    int step = step_p[0];
    int valid = (step >= 0 && step < NSTEPS);
    int sc = valid ? step : 0;
    const float* xr = x + wave * DIM + lane * 16;
    float xf[16];
#pragma unroll
    for (int q = 0; q < 4; q++) {
        float4 v4 = *(const float4*)(xr + q * 4);
        xf[q * 4 + 0] = v4.x; xf[q * 4 + 1] = v4.y;
        xf[q * 4 + 2] = v4.z; xf[q * 4 + 3] = v4.w;
    }
    float sums[8];
#pragma unroll
    for (int j = 0; j < 8; j++) {
        const float* ar = (j < 4 ? Aq + sc * RANK * DIM + j * DIM
                                 : Av + sc * RANK * DIM + (j - 4) * DIM) + lane * 16;
        float s = 0.f;
#pragma unroll
        for (int q = 0; q < 4; q++) {
            float4 a4 = *(const float4*)(ar + q * 4);
            s += xf[q * 4 + 0] * a4.x + xf[q * 4 + 1] * a4.y
               + xf[q * 4 + 2] * a4.z + xf[q * 4 + 3] * a4.w;
        }
#pragma unroll
        for (int o = 32; o > 0; o >>= 1) s += __shfl_xor(s, o, 64);
        sums[j] = s;
    }
    if (!valid) {
#pragma unroll
        for (int j = 0; j < 8; j++) sums[j] = 0.f;
    }
    if (lane == 0) {
        tq[wave * 4 + 0] = sums[0]; tq[wave * 4 + 1] = sums[1];
        tq[wave * 4 + 2] = sums[2]; tq[wave * 4 + 3] = sums[3];
        tv[wave * 4 + 0] = sums[4]; tv[wave * 4 + 1] = sums[5];
        tv[wave * 4 + 2] = sums[6]; tv[wave * 4 + 3] = sums[7];
    }
}

// ---------------- GEMM: m97 structure — single LDS buffer, 2 barriers/K-step,
// global_load_lds(16B) staging into frag-linear layout. C = A * B^T.
template<bool CF32>
__global__ __launch_bounds__(256) void k_gemm(
    const u16* __restrict__ A, const u16* __restrict__ B,
    void* __restrict__ Cptr, int Ntiles, int N)
{
    __shared__ __align__(16) u16 As[8192];
    __shared__ __align__(16) u16 Bs[8192];
    int bx = blockIdx.x;
    int bn = bx % Ntiles, bm = bx / Ntiles;
    int t = threadIdx.x, lane = t & 63, w = t >> 6;
    int wy = w >> 1, wx = w & 1;
    int wb = t & ~63;                 // w*64, wave-uniform
    f32x4 acc[4][4];
#pragma unroll
    for (int i = 0; i < 4; i++)
#pragma unroll
        for (int j = 0; j < 4; j++) acc[i][j] = (f32x4){0.f, 0.f, 0.f, 0.f};

    // per-thread global offsets for the 4 frag-linear chunks (idx = u*256+t)
    int goff[4];
#pragma unroll
    for (int u = 0; u < 4; u++) {
        int idx = u * 256 + t;
        int grp = idx >> 6;
        int mt = grp >> 1, c = grp & 1;
        int quad = (idx >> 4) & 3, m = idx & 15;
        goff[u] = (mt * 16 + m) * DIM + c * 32 + quad * 8;
    }
    const u16* Ab = A + bm * 128 * DIM;
    const u16* Bb = B + bn * 128 * DIM;

#pragma unroll 1
    for (int kb = 0; kb < 16; kb++) {
        int k0 = kb * 64;
        __syncthreads();
#pragma unroll
        for (int u = 0; u < 4; u++) {
            glds16(Ab + goff[u] + k0, As + (u * 256 + wb) * 8);
            glds16(Bb + goff[u] + k0, Bs + (u * 256 + wb) * 8);
        }
        __syncthreads();
#pragma unroll
        for (int c = 0; c < 2; c++) {
            bf16x8 af[4], bfr[4];
#pragma unroll
            for (int i = 0; i < 4; i++) {
                int mt = wy * 4 + i;
                af[i] = *(bf16x8*)(As + ((mt * 2 + c) * 64 + lane) * 8);
                int nt = wx * 4 + i;
                bfr[i] = *(bf16x8*)(Bs + ((nt * 2 + c) * 64 + lane) * 8);
            }
#pragma unroll
            for (int i = 0; i < 4; i++)
#pragma unroll
                for (int j = 0; j < 4; j++)
                    acc[i][j] = __builtin_amdgcn_mfma_f32_16x16x32_bf16(af[i], bfr[j], acc[i][j], 0, 0, 0);
        }
    }
    int quad = lane >> 4, n16 = lane & 15;
#pragma unroll
    for (int i = 0; i < 4; i++) {
#pragma unroll
        for (int j = 0; j < 4; j++) {
            int col = bn * 128 + wx * 64 + j * 16 + n16;
#pragma unroll
            for (int r = 0; r < 4; r++) {
                int rowm = bm * 128 + wy * 64 + i * 16 + quad * 4 + r;
                if (CF32) ((float*)Cptr)[rowm * N + col] = acc[i][j][r];
                else      ((u16*)Cptr)[rowm * N + col] = f2bf(acc[i][j][r]);
            }
        }
    }
}

// ---------------- K_POST: fused [RMSNorm+RoPE in-place | v-LoRA+transpose] ---
#define NR_BLOCKS 20480
__global__ __launch_bounds__(256) void k_post(
    u16* __restrict__ qkv,
    const float* __restrict__ tq, const float* __restrict__ Bq,
    const float* __restrict__ gain,
    const float* __restrict__ tv, const float* __restrict__ Bv,
    const int* __restrict__ step_p, u16* __restrict__ vt)
{
    __shared__ __align__(16) u16 tile[64 * 64];
    int bx = blockIdx.x;
    int step = step_p[0];
    int valid = (step >= 0 && step < NSTEPS);
    int sc = valid ? step : 0;
    if (bx < NR_BLOCKS) {
        int wid = (bx * 256 + threadIdx.x) >> 6;
        int lane = threadIdx.x & 63;
        float val, postmul;
        u16* ptr;
        int s;
        if (wid < BATCH * NH * SEQ) {
            int b = wid >> 15;
            int h = (wid >> 11) & 15;
            s = wid & 2047;
            int row = b * SEQ + s;
            ptr = qkv + row * 1536 + h * HD + lane;
            val = bf2f(*ptr);
            const float* tr = tq + row * 4;
            float4 br = *(const float4*)(Bq + sc * DIM * RANK + (h * HD + lane) * RANK);
            val += tr[0] * br.x + tr[1] * br.y + tr[2] * br.z + tr[3] * br.w;
            postmul = gain[h] * 0.125f * 1.4426950408889634f;   // gain/sqrt(64)*log2e
        } else {
            int wk = wid - BATCH * NH * SEQ;
            int b = wk >> 13;
            int h = (wk >> 11) & 3;
            s = wk & 2047;
            int row = b * SEQ + s;
            ptr = qkv + row * 1536 + 1024 + h * HD + lane;
            val = bf2f(*ptr);
            postmul = 1.f;
        }
        float ss = val * val;
#pragma unroll
        for (int o = 32; o > 0; o >>= 1) ss += __shfl_xor(ss, o, 64);
        float rr = rsqrtf(ss * (1.f / 64.f) + 1.1920928955078125e-7f);
        float vn = val * rr;
        float partner = __shfl_xor(vn, 16, 64);
        float res;
        if (lane < 32) {
            int i = lane & 15;
            float invf = exp2f(-(float)i * 0.8304820237218405f);  // log2(10000)/16
            float ang = (float)s * invf;
            float cs = cosf(ang), sn = sinf(ang);
            res = (lane < 16) ? (vn * cs + partner * sn) : (-partner * sn + vn * cs);
        } else {
            res = vn;
        }
        *ptr = f2bf(res * postmul);
        return;
    }
    // ---- v transpose path ----
    int vb = bx - NR_BLOCKS;
    int st = vb & 31, g = (vb >> 5) & 3, b = vb >> 7;
    int t = threadIdx.x;
    int s_l = t & 63, dq = t >> 6;
    int row = b * SEQ + st * 64 + s_l;
    const float* tr = tv + row * 4;
    float t0 = tr[0], t1 = tr[1], t2 = tr[2], t3 = tr[3];
    const u16* src = qkv + row * 1536 + 1280 + g * HD + dq * 16;
#pragma unroll
    for (int e = 0; e < 16; e++) {
        int d = dq * 16 + e;
        float4 br = *(const float4*)(Bv + sc * (NKV * HD) * RANK + (g * HD + d) * RANK);
        float v = bf2f(src[e]) + t0 * br.x + t1 * br.y + t2 * br.z + t3 * br.w;
        tile[d * 64 + s_l] = f2bf(v);
    }
    __syncthreads();
#pragma unroll
    for (int u = 0; u < 2; u++) {
        int chunk = u * 256 + t;
        int d = chunk >> 3, scn = chunk & 7;
        *(uint4*)(vt + ((b * NKV + g) * HD + d) * SEQ + st * 64 + scn * 8) =
            *(uint4*)(tile + d * 64 + scn * 8);
    }
}

// ---------------- ATT: flash attention with STATIC-MAX softmax --------------
// RMS-normed q,k bound logits: |s| <= 11.55*|gain| -> fixed M. No running max,
// no alpha rescale, no per-tile reductions. Block = (b,h,qtile64), 4 waves;
// K/V tiles staged via global_load_lds into XOR-swizzled row-major LDS.
__global__ __launch_bounds__(256) void k_attn(
    const u16* __restrict__ qkv, const u16* __restrict__ vt,
    const float* __restrict__ gain, u16* __restrict__ y)
{
    __shared__ __align__(16) u16 kf[4096];       // [64 keys][8 chunks^swz]
    __shared__ __align__(16) u16 vf[4096];       // [64 d][8 chunks^swz]
    __shared__ __align__(16) u16 pb[4][1024];    // per-wave P^T, B-frag linear
    int bx = blockIdx.x;
    int qt = 31 - (bx & 31);                     // longest blocks first
    int h = (bx >> 5) & 15, b = bx >> 9;
    int g = h >> 2;
    int t = threadIdx.x, lane = t & 63, w = t >> 6, wb = t & ~63;
    int quad = lane >> 4, n16 = lane & 15;
    int qrow = qt * 64 + w * 16 + n16;
    float negM = -11.67f * fabsf(gain[h]);       // static softmax max bound

    const u16* kbase = qkv + b * SEQ * 1536 + 1024 + g * HD;   // K rows stride 1536
    const u16* vbase = vt + (b * NKV + g) * HD * SEQ;          // V^T rows stride 2048
    const u16* qp = qkv + (b * SEQ + qrow) * 1536 + h * HD + quad * 8;
    bf16x8 qlo = *(const bf16x8*)qp;
    bf16x8 qhi = *(const bf16x8*)(qp + 32);

    // staging slot offsets: slot s holds row r=s>>3, global chunk c=(s&7)^(r&7)
    int koff[2], voff[2];
#pragma unroll
    for (int i = 0; i < 2; i++) {
        int s = i * 256 + t;
        int r = s >> 3, cc = s & 7;
        int c = cc ^ (r & 7);
        koff[i] = r * 1536 + c * 8;
        voff[i] = r * 2048 + c * 8;
    }
    // frag-read swizzled chunk offsets (16-B slots): row n16 within 16-group
    int swb = n16 & 7;
    int o0 = n16 * 8 + (quad ^ swb);             // key/d chunk c2=0
    int o1 = n16 * 8 + ((4 + quad) ^ swb);       // c2=1

    f32x4 acc[4];
#pragma unroll
    for (int i = 0; i < 4; i++) acc[i] = (f32x4){0.f, 0.f, 0.f, 0.f};
    float ps = 0.f;
    u16* pw = pb[w];
    int ntiles = qt + 1;

#pragma unroll 1
    for (int kt = 0; kt < ntiles; kt++) {
        int k0 = kt * 64;
        __syncthreads();                          // prior tile's LDS reads done
        const u16* kp = kbase + k0 * 1536;
        const u16* vp = vbase + k0;
        glds16(kp + koff[0], kf + wb * 8);
        glds16(kp + koff[1], kf + (256 + wb) * 8);
        glds16(vp + voff[0], vf + wb * 8);
        glds16(vp + voff[1], vf + (256 + wb) * 8);
        __syncthreads();                          // vmcnt drained at barrier
        // S^T = K * Q^T : D[key][q]
        f32x4 st[4];
#pragma unroll
        for (int nt = 0; nt < 4; nt++) {
            f32x4 sa = (f32x4){0.f, 0.f, 0.f, 0.f};
            sa = __builtin_amdgcn_mfma_f32_16x16x32_bf16(*(bf16x8*)(kf + (nt * 128 + o0) * 8), qlo, sa, 0, 0, 0);
            sa = __builtin_amdgcn_mfma_f32_16x16x32_bf16(*(bf16x8*)(kf + (nt * 128 + o1) * 8), qhi, sa, 0, 0, 0);
            st[nt] = sa;
        }
        // p = exp2(s - M); causal zero on diagonal tile; per-lane l accumulation
        float p[4][4];
        if (kt == ntiles - 1) {
#pragma unroll
            for (int nt = 0; nt < 4; nt++)
#pragma unroll
                for (int r = 0; r < 4; r++) {
                    int key = k0 + nt * 16 + quad * 4 + r;
                    float e = exp2f(st[nt][r] + negM);
                    e = (key > qrow) ? 0.f : e;
                    p[nt][r] = e;
                    ps += e;
                }
        } else {
#pragma unroll
            for (int nt = 0; nt < 4; nt++)
#pragma unroll
                for (int r = 0; r < 4; r++) {
                    float e = exp2f(st[nt][r] + negM);
                    p[nt][r] = e;
                    ps += e;
                }
        }
        // P^T -> per-wave LDS in B-frag linear layout
#pragma unroll
        for (int nt = 0; nt < 4; nt++) {
            u32 lo = pk2(p[nt][0], p[nt][1]);
            u32 hi = pk2(p[nt][2], p[nt][3]);
            int ck = nt >> 1;
            int qbk = (nt & 1) * 2 + (quad >> 1);
            int byteoff = (ck * 64 + qbk * 16 + n16) * 16 + (quad & 1) * 8;
            *(uint2*)((char*)pw + byteoff) = make_uint2(lo, hi);
        }
        asm volatile("s_waitcnt lgkmcnt(0)" ::: "memory");
        // Y^T += V^T * P^T
#pragma unroll
        for (int ck = 0; ck < 2; ck++) {
            bf16x8 pfr = *(bf16x8*)(pw + (ck * 64 + lane) * 8);
            int oo = ck ? o1 : o0;
#pragma unroll
            for (int dt = 0; dt < 4; dt++)
                acc[dt] = __builtin_amdgcn_mfma_f32_16x16x32_bf16(*(bf16x8*)(vf + (dt * 128 + oo) * 8), pfr, acc[dt], 0, 0, 0);
        }
        asm volatile("" ::: "memory");
    }
    // final l per q-col: in-lane ps + across the 4 quads holding this col
    ps += __shfl_xor(ps, 16, 64);
    ps += __shfl_xor(ps, 32, 64);
    float li = 1.f / ps;
#pragma unroll
    for (int dt = 0; dt < 4; dt++) {
        uint2 o = make_uint2(pk2(acc[dt][0] * li, acc[dt][1] * li),
                             pk2(acc[dt][2] * li, acc[dt][3] * li));
        int d = dt * 16 + quad * 4;
        *(uint2*)(y + (b * SEQ + qrow) * DIM + h * HD + d) = o;
    }
}

// ---------------------------------------------------------------------------
extern "C" void kernel_launch(void* const* d_in, const int* in_sizes, int n_in,
                              void* d_out, int out_size, void* d_ws, size_t ws_size,
                              hipStream_t stream)
{
    (void)in_sizes; (void)n_in; (void)out_size; (void)ws_size;
    const float* x     = (const float*)d_in[0];
    const float* Wq    = (const float*)d_in[1];
    const float* Wk    = (const float*)d_in[2];
    const float* Wv    = (const float*)d_in[3];
    const float* Wproj = (const float*)d_in[4];
    const float* qgain = (const float*)d_in[5];
    const float* Aq    = (const float*)d_in[6];
    const float* Bq    = (const float*)d_in[7];
    const float* Av    = (const float*)d_in[8];
    const float* Bv    = (const float*)d_in[9];
    const int*   step  = (const int*)d_in[10];

    // ws layout (25.1 MB): cvt [xb 8MB | Wqkv 3MB | Wproj 2MB] + qkv 12MB + tq/tv
    // reuse: y overlays xb; vt overlays Wqkv.
    char* ws = (char*)d_ws;
    u16* wsbf = (u16*)ws;
    u16* xb   = wsbf;
    u16* wf   = wsbf + XN;
    u16* wp   = wsbf + WV_END;
    u16* qkv  = (u16*)(ws + 13631488);
    float* tq = (float*)(ws + 26214400);
    float* tv = tq + 16384;
    u16* y    = xb;
    u16* vt   = wf;

    k_prep<<<CVT_BLOCKS + LORA_BLOCKS, 256, 0, stream>>>(x, Wq, Wk, Wv, Wproj, wsbf,
                                                         Aq, Av, step, tq, tv);
    k_gemm<false><<<384, 256, 0, stream>>>(xb, wf, qkv, 12, 1536);      // fused qkv
    k_post<<<NR_BLOCKS + 256, 256, 0, stream>>>(qkv, tq, Bq, qgain, tv, Bv, step, vt);
    k_attn<<<1024, 256, 0, stream>>>(qkv, vt, qgain, y);
    k_gemm<true><<<256, 256, 0, stream>>>(y, wp, d_out, 8, DIM);        // out proj
}